// Round 3
// baseline (99.435 us; speedup 1.0000x reference)
//
#include <hip/hip_runtime.h>

// EquivariantDense: out[b, i*O4+o] = sum_j sum_k w_{j+1}[b,o,k] * x[b, ((i+j)%4)*K + k]
// B=8, O4=1024, K=4096, N=4*K=16384. Output (B, 4*O4) fp32.
// Memory-bound: 512 MiB of weights streamed once per call; x (512 KiB) L2-resident.
//
// R3 = R2 with compile fix: __builtin_nontemporal_load needs a native clang
// vector type, not HIP_vector_type. NT loads on w3/w4 so the Infinity Cache
// (256 MiB) retains w1+w2 (exactly 256 MiB) across graph replays.

#define B_DIM 8
#define O4_DIM 1024
#define K_DIM 4096
#define N_DIM 16384
#define TILE_O 4

typedef float floatx4 __attribute__((ext_vector_type(4)));

template <bool NT>
__device__ __forceinline__ void dot_loop(const floatx4* __restrict__ wbase,
                                         const floatx4* __restrict__ xbase,
                                         float acc[TILE_O][4], int lane)
{
    // K_DIM/4 = 1024 float4 per row; 64 lanes -> 16 iterations.
#pragma unroll 4
    for (int it = 0; it < 16; ++it) {
        const int idx = it * 64 + lane;
        floatx4 xv[4];
#pragma unroll
        for (int m = 0; m < 4; ++m)
            xv[m] = xbase[m * 1024 + idx];
#pragma unroll
        for (int o = 0; o < TILE_O; ++o) {
            const floatx4* p = wbase + o * 1024 + idx;
            floatx4 wv;
            if (NT) wv = __builtin_nontemporal_load(p);
            else    wv = *p;
#pragma unroll
            for (int m = 0; m < 4; ++m) {
                acc[o][m] += wv.x * xv[m].x;
                acc[o][m] += wv.y * xv[m].y;
                acc[o][m] += wv.z * xv[m].z;
                acc[o][m] += wv.w * xv[m].w;
            }
        }
    }
}

__global__ __launch_bounds__(256) void eq_dense_kernel(
    const float* __restrict__ x,
    const float* __restrict__ w1,
    const float* __restrict__ w2,
    const float* __restrict__ w3,
    const float* __restrict__ w4,
    float* __restrict__ out)
{
    const int b    = blockIdx.y;
    const int o0   = blockIdx.x * TILE_O;
    const int tid  = threadIdx.x;
    const int j    = tid >> 6;   // wave id = which weight tensor
    const int lane = tid & 63;

    const float* wsel = (j == 0) ? w1 : (j == 1) ? w2 : (j == 2) ? w3 : w4;
    const floatx4* wbase = reinterpret_cast<const floatx4*>(
        wsel + ((size_t)b * O4_DIM + o0) * K_DIM);
    const floatx4* xbase = reinterpret_cast<const floatx4*>(
        x + (size_t)b * N_DIM);

    float acc[TILE_O][4];
#pragma unroll
    for (int o = 0; o < TILE_O; ++o)
#pragma unroll
        for (int m = 0; m < 4; ++m)
            acc[o][m] = 0.0f;

    if (j >= 2) dot_loop<true >(wbase, xbase, acc, lane);   // w3/w4: streaming
    else        dot_loop<false>(wbase, xbase, acc, lane);   // w1/w2: L3-resident

    // Wave-level butterfly reduction of all 16 accumulators (64 lanes).
#pragma unroll
    for (int o = 0; o < TILE_O; ++o)
#pragma unroll
        for (int m = 0; m < 4; ++m) {
            float v = acc[o][m];
            v += __shfl_xor(v, 32, 64);
            v += __shfl_xor(v, 16, 64);
            v += __shfl_xor(v, 8, 64);
            v += __shfl_xor(v, 4, 64);
            v += __shfl_xor(v, 2, 64);
            v += __shfl_xor(v, 1, 64);
            acc[o][m] = v;
        }

    __shared__ float red[4][TILE_O][4];  // [j][o][m]
    if (lane == 0) {
#pragma unroll
        for (int o = 0; o < TILE_O; ++o)
#pragma unroll
            for (int m = 0; m < 4; ++m)
                red[j][o][m] = acc[o][m];
    }
    __syncthreads();

    // out[b, i*O4 + o0+o] = sum_j red[j][o][(i+j)&3]
    if (tid < TILE_O * 4) {
        const int o = tid & (TILE_O - 1);
        const int i = tid >> 2;
        float v = 0.0f;
#pragma unroll
        for (int jj = 0; jj < 4; ++jj)
            v += red[jj][o][(i + jj) & 3];
        out[(size_t)b * (4 * O4_DIM) + (size_t)i * O4_DIM + (o0 + o)] = v;
    }
}

extern "C" void kernel_launch(void* const* d_in, const int* in_sizes, int n_in,
                              void* d_out, int out_size, void* d_ws, size_t ws_size,
                              hipStream_t stream) {
    const float* x  = (const float*)d_in[0];
    const float* w1 = (const float*)d_in[1];
    const float* w2 = (const float*)d_in[2];
    const float* w3 = (const float*)d_in[3];
    const float* w4 = (const float*)d_in[4];
    float* out = (float*)d_out;

    dim3 grid(O4_DIM / TILE_O, B_DIM);  // (256, 8) = 2048 blocks
    dim3 block(256);
    eq_dense_kernel<<<grid, block, 0, stream>>>(x, w1, w2, w3, w4, out);
}

// Round 4
// 94.284 us; speedup vs baseline: 1.0546x; 1.0546x over previous
//
#include <hip/hip_runtime.h>

// EquivariantDense: out[b, i*O4+o] = sum_j sum_k w_{j+1}[b,o,k] * x[b, ((i+j)%4)*K + k]
// B=8, O4=1024, K=4096, N=4*K=16384. Output (B, 4*O4) fp32.
// Memory-bound: 512 MiB of weights streamed once per call; x (64 KiB per batch).
//
// R4: revert NT (neutral). Stage x[b] (64 KiB) in LDS once per block so the
// inner loop's x reads use the DS pipe (lgkmcnt) instead of competing with the
// weight stream on the VMEM pipe (vmcnt). Weight loads get the full vector-
// memory path and an unmixed waitcnt chain.

#define B_DIM 8
#define O4_DIM 1024
#define K_DIM 4096
#define N_DIM 16384
#define TILE_O 4

typedef float floatx4 __attribute__((ext_vector_type(4)));

__global__ __launch_bounds__(256) void eq_dense_kernel(
    const float* __restrict__ x,
    const float* __restrict__ w1,
    const float* __restrict__ w2,
    const float* __restrict__ w3,
    const float* __restrict__ w4,
    float* __restrict__ out)
{
    const int b    = blockIdx.y;
    const int o0   = blockIdx.x * TILE_O;
    const int tid  = threadIdx.x;
    const int j    = tid >> 6;   // wave id = which weight tensor
    const int lane = tid & 63;

    __shared__ floatx4 xs[N_DIM / 4];        // 64 KiB: all of x[b]
    __shared__ float red[4][TILE_O][4];      // [j][o][m]

    // Stage x[b] into LDS: 4096 float4 / 256 threads = 16 per thread, coalesced.
    {
        const floatx4* xg = reinterpret_cast<const floatx4*>(x + (size_t)b * N_DIM);
#pragma unroll
        for (int r = 0; r < 16; ++r)
            xs[r * 256 + tid] = xg[r * 256 + tid];
    }
    __syncthreads();

    const float* wsel = (j == 0) ? w1 : (j == 1) ? w2 : (j == 2) ? w3 : w4;
    const floatx4* wbase = reinterpret_cast<const floatx4*>(
        wsel + ((size_t)b * O4_DIM + o0) * K_DIM);

    float acc[TILE_O][4];
#pragma unroll
    for (int o = 0; o < TILE_O; ++o)
#pragma unroll
        for (int m = 0; m < 4; ++m)
            acc[o][m] = 0.0f;

    // K_DIM/4 = 1024 float4 per row; 64 lanes -> 16 iterations.
#pragma unroll 4
    for (int it = 0; it < 16; ++it) {
        const int idx = it * 64 + lane;
        floatx4 wv[TILE_O];
#pragma unroll
        for (int o = 0; o < TILE_O; ++o)
            wv[o] = wbase[o * 1024 + idx];      // VMEM: pure weight stream
        floatx4 xv[4];
#pragma unroll
        for (int m = 0; m < 4; ++m)
            xv[m] = xs[m * 1024 + idx];         // DS pipe, conflict-free b128
#pragma unroll
        for (int o = 0; o < TILE_O; ++o)
#pragma unroll
            for (int m = 0; m < 4; ++m) {
                acc[o][m] += wv[o].x * xv[m].x;
                acc[o][m] += wv[o].y * xv[m].y;
                acc[o][m] += wv[o].z * xv[m].z;
                acc[o][m] += wv[o].w * xv[m].w;
            }
    }

    // Wave-level butterfly reduction of all 16 accumulators (64 lanes).
#pragma unroll
    for (int o = 0; o < TILE_O; ++o)
#pragma unroll
        for (int m = 0; m < 4; ++m) {
            float v = acc[o][m];
            v += __shfl_xor(v, 32, 64);
            v += __shfl_xor(v, 16, 64);
            v += __shfl_xor(v, 8, 64);
            v += __shfl_xor(v, 4, 64);
            v += __shfl_xor(v, 2, 64);
            v += __shfl_xor(v, 1, 64);
            acc[o][m] = v;
        }

    __syncthreads();  // red[] reuse barrier (cheap; also separates xs reads)
    if (lane == 0) {
#pragma unroll
        for (int o = 0; o < TILE_O; ++o)
#pragma unroll
            for (int m = 0; m < 4; ++m)
                red[j][o][m] = acc[o][m];
    }
    __syncthreads();

    // out[b, i*O4 + o0+o] = sum_j red[j][o][(i+j)&3]
    if (tid < TILE_O * 4) {
        const int o = tid & (TILE_O - 1);
        const int i = tid >> 2;
        float v = 0.0f;
#pragma unroll
        for (int jj = 0; jj < 4; ++jj)
            v += red[jj][o][(i + jj) & 3];
        out[(size_t)b * (4 * O4_DIM) + (size_t)i * O4_DIM + (o0 + o)] = v;
    }
}

extern "C" void kernel_launch(void* const* d_in, const int* in_sizes, int n_in,
                              void* d_out, int out_size, void* d_ws, size_t ws_size,
                              hipStream_t stream) {
    const float* x  = (const float*)d_in[0];
    const float* w1 = (const float*)d_in[1];
    const float* w2 = (const float*)d_in[2];
    const float* w3 = (const float*)d_in[3];
    const float* w4 = (const float*)d_in[4];
    float* out = (float*)d_out;

    dim3 grid(O4_DIM / TILE_O, B_DIM);  // (256, 8) = 2048 blocks
    dim3 block(256);
    eq_dense_kernel<<<grid, block, 0, stream>>>(x, w1, w2, w3, w4, out);
}